// Round 14
// baseline (35.878 us; speedup 1.0000x reference)
//
#include <hip/hip_runtime.h>
#include <hip/hip_bf16.h>

#define NB 32
#define SEQ 1024
#define DIM 64
#define LDP 72   // padded LDS stride: 144B rows, 16B-aligned (qkv only)

typedef __attribute__((ext_vector_type(8))) short bf16x8;
typedef __attribute__((ext_vector_type(8))) unsigned short ushort8;
typedef __attribute__((ext_vector_type(4))) float f32x4;

#define MFMA16 __builtin_amdgcn_mfma_f32_16x16x32_bf16

__device__ __forceinline__ unsigned short f2bf(float f) {
    union { float f; unsigned u; } c; c.f = f;
    return (unsigned short)((c.u + 0x7FFFu + ((c.u >> 16) & 1u)) >> 16);  // RNE
}
__device__ __forceinline__ float bf2f(unsigned short u) {
    union { unsigned u; float f; } c; c.u = (unsigned)u << 16;
    return c.f;
}
__device__ __forceinline__ unsigned pk2(float a, float b) {
    return (unsigned)f2bf(a) | ((unsigned)f2bf(b) << 16);
}
__device__ __forceinline__ bf16x8 cvt8(float4 a, float4 b) {
    bf16x8 r;
    r[0] = (short)f2bf(a.x); r[1] = (short)f2bf(a.y);
    r[2] = (short)f2bf(a.z); r[3] = (short)f2bf(a.w);
    r[4] = (short)f2bf(b.x); r[5] = (short)f2bf(b.y);
    r[6] = (short)f2bf(b.z); r[7] = (short)f2bf(b.w);
    return r;
}

// ---------------- Kernel 1: QKV projection (round-13 version) --------------
__global__ __launch_bounds__(256) void qkv_proj(
    const float* __restrict__ x, const float* __restrict__ Wq,
    const float* __restrict__ Wk, const float* __restrict__ Wv,
    unsigned short* __restrict__ qg, unsigned short* __restrict__ kg,
    unsigned short* __restrict__ vtg)
{
    __shared__ unsigned short ws[3][64 * LDP];
    __shared__ unsigned short tr[3][64 * LDP];
    const int tid = threadIdx.x;
    const int w = tid >> 6, lane = tid & 63;
    const int l15 = lane & 15, l4 = lane >> 4;
    const int orig = blockIdx.x;
    const int blkid = (orig & 7) * 64 + (orig >> 3);  // XCD-chunked, bijective
    const size_t row0 = (size_t)blkid * 64;

    {   // stage W matrices as bf16 (padded rows)
        const int r = tid >> 2, c = (tid & 3) * 16;
        const float* srcs[3] = {Wq, Wk, Wv};
        #pragma unroll
        for (int m = 0; m < 3; ++m) {
            const float* s = srcs[m] + r * DIM + c;
            const float4 f0 = ((const float4*)s)[0], f1 = ((const float4*)s)[1];
            const float4 f2 = ((const float4*)s)[2], f3 = ((const float4*)s)[3];
            *(bf16x8*)&ws[m][r * LDP + c]     = cvt8(f0, f1);
            *(bf16x8*)&ws[m][r * LDP + c + 8] = cvt8(f2, f3);
        }
    }
    const float* xp = x + (row0 + w * 16 + l15) * DIM + l4 * 8;
    const float4 x0 = ((const float4*)xp)[0];
    const float4 x1 = ((const float4*)xp)[1];
    const float4 x2 = ((const float4*)(xp + 32))[0];
    const float4 x3 = ((const float4*)(xp + 32))[1];
    const bf16x8 xa0 = cvt8(x0, x1), xa1 = cvt8(x2, x3);
    __syncthreads();

    #pragma unroll
    for (int m = 0; m < 3; ++m) {
        #pragma unroll
        for (int nb = 0; nb < 4; ++nb) {
            const bf16x8 b0 = *(const bf16x8*)&ws[m][(nb * 16 + l15) * LDP + l4 * 8];
            const bf16x8 b1 = *(const bf16x8*)&ws[m][(nb * 16 + l15) * LDP + 32 + l4 * 8];
            f32x4 a = {0.f, 0.f, 0.f, 0.f};
            a = MFMA16(xa0, b0, a, 0, 0, 0);
            a = MFMA16(xa1, b1, a, 0, 0, 0);
            #pragma unroll
            for (int r = 0; r < 4; ++r) {
                const int orow = w * 16 + l4 * 4 + r, ocol = nb * 16 + l15;
                const float v = (m == 0) ? a[r] * 0.125f : a[r];
                if (m == 2) tr[2][ocol * LDP + orow] = f2bf(v);  // v transposed
                else        tr[m][orow * LDP + ocol] = f2bf(v);
            }
        }
    }
    __syncthreads();
    {   // fully-coalesced stores
        const int r = tid >> 2, c = (tid & 3) * 16;
        const size_t b = row0 >> 10; const int s0 = (int)(row0 & 1023);
        unsigned short* qdst = qg + (row0 + r) * DIM + c;
        *(bf16x8*)qdst       = *(const bf16x8*)&tr[0][r * LDP + c];
        *(bf16x8*)(qdst + 8) = *(const bf16x8*)&tr[0][r * LDP + c + 8];
        unsigned short* kdst = kg + (row0 + r) * DIM + c;
        *(bf16x8*)kdst       = *(const bf16x8*)&tr[1][r * LDP + c];
        *(bf16x8*)(kdst + 8) = *(const bf16x8*)&tr[1][r * LDP + c + 8];
        unsigned short* vdst = vtg + (b * 64 + r) * SEQ + s0 + c;
        *(bf16x8*)vdst       = *(const bf16x8*)&tr[2][r * LDP + c];
        *(bf16x8*)(vdst + 8) = *(const bf16x8*)&tr[2][r * LDP + c + 8];
    }
}

// ---------------- Kernel 2: split-K flash attention, 8-wave blocks ---------
// Block = (b, 128-row q-tile i, chunk of <=4 k-tiles), 8 waves / 512 thr.
// One 64x64 K/V tile shared by 8 waves: staging+barrier cost per wave
// halves. Waves 0-3 skip tile 2i+1 (fully causal-masked); waves 4-7 treat
// it as diagonal. Grid 640 = one scheduling round at 3 blocks/CU.
__global__ __launch_bounds__(512, 6) void attn_partial(
    const unsigned short* __restrict__ qg, const unsigned short* __restrict__ kg,
    const unsigned short* __restrict__ vtg, float* __restrict__ out,
    unsigned short* __restrict__ part_acc, float* __restrict__ part_ml)
{
    __shared__ unsigned short Ks[2][64 * 64];
    __shared__ unsigned short Vs[2][64 * 64];
    __shared__ unsigned short Ps[8][16 * 64];

    const int tid = threadIdx.x;
    const int w = tid >> 6, lane = tid & 63;
    const int l15 = lane & 15, l4 = lane >> 4;

    const int orig = blockIdx.x;
    const int blk = (orig & 7) * 80 + (orig >> 3);  // 640 = 8*80, bijective
    const int b = blk / 20;
    const int c = 19 - (blk % 20);       // heavy-first LPT
    int i, ch;                            // q-tile index (128 rows), chunk
    if (c < 1)       { i = 0; ch = 0; }
    else if (c < 2)  { i = 1; ch = 0; }
    else if (c < 4)  { i = 2; ch = c - 2; }
    else if (c < 6)  { i = 3; ch = c - 4; }
    else if (c < 9)  { i = 4; ch = c - 6; }
    else if (c < 12) { i = 5; ch = c - 9; }
    else if (c < 16) { i = 6; ch = c - 12; }
    else             { i = 7; ch = c - 16; }
    const int nch = (2 * i + 5) >> 2;     // 1,1,2,2,3,3,4,4
    const int ntiles = 2 * i + 2;
    const int q0 = i * 128;
    const int t0 = ch * 4;
    const int t1 = min(t0 + 4, ntiles);

    const int skip_tt = (w < 4) ? (2 * i + 1) : -1;   // fully-masked tile
    const int diag_tt = (w < 4) ? (2 * i) : (2 * i + 1);

    // Q fragments (B-operand), scale pre-folded; wave w owns rows q0+w*16..+15
    const unsigned short* qp = qg + ((size_t)(b * SEQ + q0 + w * 16 + l15)) * DIM + l4 * 8;
    const bf16x8 qf0 = *(const bf16x8*)qp;
    const bf16x8 qf1 = *(const bf16x8*)(qp + 32);

    // staging: 512 threads, one bf16x8 each per matrix; row sr, chunk sc8
    const int sr = tid >> 3, sc8 = tid & 7;
    const unsigned short* kbase = kg + (size_t)b * SEQ * DIM + (size_t)sr * DIM + sc8 * 8;
    const unsigned short* vbase = vtg + ((size_t)b * 64 + sr) * SEQ + sc8 * 8;
    const int woff = sr * 64 + ((sc8 ^ (sr & 7)) << 3);

    // read-side swizzled chunk offset (row&7 == l15&7 for all frag rows)
    const int rc0 = (l4 ^ (l15 & 7)) << 3;

    // prologue: stage tile t0 into buffer 0
    bf16x8 rk = *(const bf16x8*)(kbase + (size_t)t0 * 64 * DIM);
    bf16x8 rv = *(const bf16x8*)(vbase + (size_t)t0 * 64);
    *(bf16x8*)&Ks[0][woff] = rk;
    *(bf16x8*)&Vs[0][woff] = rv;
    __syncthreads();

    f32x4 acc[4] = {};
    float m_run = -1e30f, l_run = 0.f;

    for (int tt = t0; tt < t1; ++tt) {
        const int cur = (tt - t0) & 1;
        const bool pf = (tt + 1 < t1);
        if (pf) {
            const size_t kn = (size_t)(tt + 1) * 64;
            rk = *(const bf16x8*)(kbase + kn * DIM);
            rv = *(const bf16x8*)(vbase + kn);
        }

        if (tt != skip_tt) {
            // S^T = K . Q : lane holds S[k=nb*16+l4*4+r][q=l15]
            f32x4 s[4];
            __builtin_amdgcn_s_setprio(1);
            #pragma unroll
            for (int nb = 0; nb < 4; ++nb) {
                const int krow = (nb * 16 + l15) * 64;
                const bf16x8 kf0 = *(const bf16x8*)&Ks[cur][krow + rc0];
                const bf16x8 kf1 = *(const bf16x8*)&Ks[cur][krow + (rc0 ^ 32)];
                f32x4 sv = {0.f, 0.f, 0.f, 0.f};
                sv = MFMA16(kf0, qf0, sv, 0, 0, 0);
                sv = MFMA16(kf1, qf1, sv, 0, 0, 0);
                s[nb] = sv;
            }
            __builtin_amdgcn_s_setprio(0);

            if (tt == diag_tt) {  // causal mask on this wave's diagonal tile
                const int qabs = q0 + w * 16 + l15;
                #pragma unroll
                for (int nb = 0; nb < 4; ++nb)
                    #pragma unroll
                    for (int r = 0; r < 4; ++r)
                        if (tt * 64 + nb * 16 + l4 * 4 + r > qabs) s[nb][r] = -1e30f;
            }

            // softmax for q-row l15: 16 in-lane + 2-shfl butterfly over l4
            float pmax = s[0][0];
            #pragma unroll
            for (int nb = 0; nb < 4; ++nb)
                #pragma unroll
                for (int r = 0; r < 4; ++r) pmax = fmaxf(pmax, s[nb][r]);
            pmax = fmaxf(pmax, __shfl_xor(pmax, 16));
            pmax = fmaxf(pmax, __shfl_xor(pmax, 32));

            const float mnew = fmaxf(m_run, pmax);
            const float scf = __expf(m_run - mnew);
            m_run = mnew;

            float psum = 0.f;
            #pragma unroll
            for (int nb = 0; nb < 4; ++nb)
                #pragma unroll
                for (int r = 0; r < 4; ++r) {
                    s[nb][r] = __expf(s[nb][r] - mnew);
                    psum += s[nb][r];
                }
            psum += __shfl_xor(psum, 16);
            psum += __shfl_xor(psum, 32);
            l_run = l_run * scf + psum;

            #pragma unroll
            for (int r = 0; r < 4; ++r) {  // acc row r = q-row l4*4+r
                const float srw = __shfl(scf, l4 * 4 + r);
                acc[0][r] *= srw; acc[1][r] *= srw; acc[2][r] *= srw; acc[3][r] *= srw;
            }

            // P -> swizzled wave-private LDS (b64), then A-frag readback
            const int psbase = l15 * 64 + (l4 & 1) * 4;
            const int pch = l4 >> 1;
            #pragma unroll
            for (int nb = 0; nb < 4; ++nb) {
                const unsigned long long v =
                    (unsigned long long)pk2(s[nb][0], s[nb][1]) |
                    ((unsigned long long)pk2(s[nb][2], s[nb][3]) << 32);
                *(unsigned long long*)&Ps[w][psbase + (((2 * nb + pch) ^ (l15 & 7)) << 3)] = v;
            }
            const bf16x8 pa0 = *(const bf16x8*)&Ps[w][l15 * 64 + rc0];
            const bf16x8 pa1 = *(const bf16x8*)&Ps[w][l15 * 64 + (rc0 ^ 32)];

            __builtin_amdgcn_s_setprio(1);
            #pragma unroll
            for (int nb2 = 0; nb2 < 4; ++nb2) {
                const int vrow = (nb2 * 16 + l15) * 64;
                const bf16x8 vb0 = *(const bf16x8*)&Vs[cur][vrow + rc0];
                const bf16x8 vb1 = *(const bf16x8*)&Vs[cur][vrow + (rc0 ^ 32)];
                acc[nb2] = MFMA16(pa0, vb0, acc[nb2], 0, 0, 0);
                acc[nb2] = MFMA16(pa1, vb1, acc[nb2], 0, 0, 0);
            }
            __builtin_amdgcn_s_setprio(0);
        }

        if (pf) {
            *(bf16x8*)&Ks[cur ^ 1][woff] = rk;
            *(bf16x8*)&Vs[cur ^ 1][woff] = rv;
        }
        __syncthreads();  // single barrier per tile
    }

    if (nch == 1) {  // i <= 1: full k-range done here, write final output
        const float inv = 1.0f / l_run;
        #pragma unroll
        for (int r = 0; r < 4; ++r) {
            const float ir = __shfl(inv, l4 * 4 + r);
            const size_t row = (size_t)(b * SEQ + q0 + w * 16 + l4 * 4 + r);
            #pragma unroll
            for (int nb2 = 0; nb2 < 4; ++nb2)
                out[row * DIM + nb2 * 16 + l15] = acc[nb2][r] * ir;
        }
    } else {         // lane-native partial: 2 coalesced bf16x8 stores
        const size_t slot = (size_t)((b * 6 + (i - 2)) * 4 + ch);
        unsigned short* pa = part_acc + slot * 8192 + (size_t)(w * 64 + lane) * 16;
        bf16x8 o0, o1;
        #pragma unroll
        for (int nb2 = 0; nb2 < 2; ++nb2)
            #pragma unroll
            for (int r = 0; r < 4; ++r) {
                o0[nb2 * 4 + r] = (short)f2bf(acc[nb2][r]);
                o1[nb2 * 4 + r] = (short)f2bf(acc[nb2 + 2][r]);
            }
        *(bf16x8*)pa       = o0;
        *(bf16x8*)(pa + 8) = o1;
        if (l4 == 0) {
            float* pm = part_ml + slot * 256;
            pm[w * 16 + l15]       = m_run;
            pm[128 + w * 16 + l15] = l_run;
        }
    }
}

// ---------------- Kernel 3: split-K combine (128-row tiles, i >= 2) --------
// 256 threads; each thread merges the 2 wave-fragments (w2, w2+4) it maps to.
__global__ __launch_bounds__(256) void combine(
    const unsigned short* __restrict__ part_acc,
    const float* __restrict__ part_ml, float* __restrict__ out)
{
    const int orig = blockIdx.x;
    const int blk = (orig & 7) * 24 + (orig >> 3);   // 192 = 8*24, bijective
    const int b = blk / 6, i2 = blk % 6;
    const int i = i2 + 2;
    const int nch = (2 * i + 5) >> 2;                // 2,2,3,3,4,4
    const int q0 = i * 128;
    const int tid = threadIdx.x;
    const int lane = tid & 63;
    const int l15 = lane & 15, l4 = lane >> 4;
    const size_t base0 = (size_t)(b * 6 + i2) * 4;

    #pragma unroll
    for (int h = 0; h < 2; ++h) {
        const int w2 = (tid >> 6) + h * 4;
        float mv[4][4], lv[4][4], M[4];
        #pragma unroll
        for (int r = 0; r < 4; ++r) M[r] = -1e30f;
        #pragma unroll
        for (int cc = 0; cc < 4; ++cc) {
            if (cc < nch) {
                const float* pm = part_ml + (base0 + cc) * 256;
                #pragma unroll
                for (int r = 0; r < 4; ++r) {
                    mv[cc][r] = pm[w2 * 16 + l4 * 4 + r];
                    lv[cc][r] = pm[128 + w2 * 16 + l4 * 4 + r];
                    M[r] = fmaxf(M[r], mv[cc][r]);
                }
            } else {
                #pragma unroll
                for (int r = 0; r < 4; ++r) { mv[cc][r] = -1e30f; lv[cc][r] = 0.f; }
            }
        }
        float o[16], L[4];
        #pragma unroll
        for (int k = 0; k < 16; ++k) o[k] = 0.f;
        #pragma unroll
        for (int r = 0; r < 4; ++r) L[r] = 0.f;
        #pragma unroll
        for (int cc = 0; cc < 4; ++cc) {
            if (cc < nch) {
                float wsc[4];
                #pragma unroll
                for (int r = 0; r < 4; ++r) {
                    wsc[r] = __expf(mv[cc][r] - M[r]);
                    L[r] += wsc[r] * lv[cc][r];
                }
                const unsigned short* pa =
                    part_acc + (base0 + cc) * 8192 + (size_t)(w2 * 64 + lane) * 16;
                const ushort8 t0 = *(const ushort8*)pa;
                const ushort8 t1 = *(const ushort8*)(pa + 8);
                #pragma unroll
                for (int k = 0; k < 8; ++k) {
                    o[k]     += wsc[k & 3] * bf2f(t0[k]);
                    o[k + 8] += wsc[k & 3] * bf2f(t1[k]);
                }
            }
        }
        float inv[4];
        #pragma unroll
        for (int r = 0; r < 4; ++r) inv[r] = 1.0f / L[r];
        #pragma unroll
        for (int nb2 = 0; nb2 < 4; ++nb2)
            #pragma unroll
            for (int r = 0; r < 4; ++r) {
                const size_t row = (size_t)(b * SEQ + q0 + w2 * 16 + l4 * 4 + r);
                out[row * DIM + nb2 * 16 + l15] = o[nb2 * 4 + r] * inv[r];
            }
    }
}

extern "C" void kernel_launch(void* const* d_in, const int* in_sizes, int n_in,
                              void* d_out, int out_size, void* d_ws, size_t ws_size,
                              hipStream_t stream) {
    const float* x  = (const float*)d_in[0];
    const float* Wq = (const float*)d_in[1];
    const float* Wk = (const float*)d_in[2];
    const float* Wv = (const float*)d_in[3];
    float* outp = (float*)d_out;

    // ws: q | k | vT (bf16, 4MB each) | part_acc (bf16, 12.6MB) | part_ml (fp32)
    unsigned short* qw  = (unsigned short*)d_ws;
    unsigned short* kw  = qw + (size_t)NB * SEQ * DIM;
    unsigned short* vtw = kw + (size_t)NB * SEQ * DIM;
    unsigned short* pacc = vtw + (size_t)NB * SEQ * DIM;
    float* pml = (float*)(pacc + (size_t)NB * 6 * 4 * 8192);

    qkv_proj<<<NB * SEQ / 64, 256, 0, stream>>>(x, Wq, Wk, Wv, qw, kw, vtw);
    attn_partial<<<NB * 20, 512, 0, stream>>>(qw, kw, vtw, outp, pacc, pml);
    combine<<<NB * 6, 256, 0, stream>>>(pacc, pml, outp);
}

// Round 15
// 31.688 us; speedup vs baseline: 1.1322x; 1.1322x over previous
//
#include <hip/hip_runtime.h>
#include <hip/hip_bf16.h>

#define NB 32
#define SEQ 1024
#define DIM 64
#define LDP 72   // padded LDS stride: 144B rows, 16B-aligned (qkv only)

typedef __attribute__((ext_vector_type(8))) short bf16x8;
typedef __attribute__((ext_vector_type(8))) unsigned short ushort8;
typedef __attribute__((ext_vector_type(4))) float f32x4;

#define MFMA16 __builtin_amdgcn_mfma_f32_16x16x32_bf16

__device__ __forceinline__ unsigned short f2bf(float f) {
    union { float f; unsigned u; } c; c.f = f;
    return (unsigned short)((c.u + 0x7FFFu + ((c.u >> 16) & 1u)) >> 16);  // RNE
}
__device__ __forceinline__ float bf2f(unsigned short u) {
    union { unsigned u; float f; } c; c.u = (unsigned)u << 16;
    return c.f;
}
__device__ __forceinline__ unsigned pk2(float a, float b) {
    return (unsigned)f2bf(a) | ((unsigned)f2bf(b) << 16);
}
__device__ __forceinline__ bf16x8 cvt8(float4 a, float4 b) {
    bf16x8 r;
    r[0] = (short)f2bf(a.x); r[1] = (short)f2bf(a.y);
    r[2] = (short)f2bf(a.z); r[3] = (short)f2bf(a.w);
    r[4] = (short)f2bf(b.x); r[5] = (short)f2bf(b.y);
    r[6] = (short)f2bf(b.z); r[7] = (short)f2bf(b.w);
    return r;
}

// LPT dispatch order for 30 chunks/batch (chunk=6 decode below), sorted by
// descending chain length: 16x 6-tile, then 5,4,4,3,3,2,2, then 7x 1-tile.
__device__ const int kOrder[30] = {
    5, 6, 8, 10, 12, 14, 16, 17, 18, 19, 21, 22, 24, 25, 27, 28,
    4, 29, 3, 26, 2, 23, 1, 7, 9, 11, 13, 15, 20, 0
};

// ---------------- Kernel 1: QKV projection (round-13 version) --------------
__global__ __launch_bounds__(256) void qkv_proj(
    const float* __restrict__ x, const float* __restrict__ Wq,
    const float* __restrict__ Wk, const float* __restrict__ Wv,
    unsigned short* __restrict__ qg, unsigned short* __restrict__ kg,
    unsigned short* __restrict__ vtg)
{
    __shared__ unsigned short ws[3][64 * LDP];
    __shared__ unsigned short tr[3][64 * LDP];
    const int tid = threadIdx.x;
    const int w = tid >> 6, lane = tid & 63;
    const int l15 = lane & 15, l4 = lane >> 4;
    const int orig = blockIdx.x;
    const int blkid = (orig & 7) * 64 + (orig >> 3);  // XCD-chunked, bijective
    const size_t row0 = (size_t)blkid * 64;

    {   // stage W matrices as bf16 (padded rows)
        const int r = tid >> 2, c = (tid & 3) * 16;
        const float* srcs[3] = {Wq, Wk, Wv};
        #pragma unroll
        for (int m = 0; m < 3; ++m) {
            const float* s = srcs[m] + r * DIM + c;
            const float4 f0 = ((const float4*)s)[0], f1 = ((const float4*)s)[1];
            const float4 f2 = ((const float4*)s)[2], f3 = ((const float4*)s)[3];
            *(bf16x8*)&ws[m][r * LDP + c]     = cvt8(f0, f1);
            *(bf16x8*)&ws[m][r * LDP + c + 8] = cvt8(f2, f3);
        }
    }
    const float* xp = x + (row0 + w * 16 + l15) * DIM + l4 * 8;
    const float4 x0 = ((const float4*)xp)[0];
    const float4 x1 = ((const float4*)xp)[1];
    const float4 x2 = ((const float4*)(xp + 32))[0];
    const float4 x3 = ((const float4*)(xp + 32))[1];
    const bf16x8 xa0 = cvt8(x0, x1), xa1 = cvt8(x2, x3);
    __syncthreads();

    #pragma unroll
    for (int m = 0; m < 3; ++m) {
        #pragma unroll
        for (int nb = 0; nb < 4; ++nb) {
            const bf16x8 b0 = *(const bf16x8*)&ws[m][(nb * 16 + l15) * LDP + l4 * 8];
            const bf16x8 b1 = *(const bf16x8*)&ws[m][(nb * 16 + l15) * LDP + 32 + l4 * 8];
            f32x4 a = {0.f, 0.f, 0.f, 0.f};
            a = MFMA16(xa0, b0, a, 0, 0, 0);
            a = MFMA16(xa1, b1, a, 0, 0, 0);
            #pragma unroll
            for (int r = 0; r < 4; ++r) {
                const int orow = w * 16 + l4 * 4 + r, ocol = nb * 16 + l15;
                const float v = (m == 0) ? a[r] * 0.125f : a[r];
                if (m == 2) tr[2][ocol * LDP + orow] = f2bf(v);  // v transposed
                else        tr[m][orow * LDP + ocol] = f2bf(v);
            }
        }
    }
    __syncthreads();
    {   // fully-coalesced stores
        const int r = tid >> 2, c = (tid & 3) * 16;
        const size_t b = row0 >> 10; const int s0 = (int)(row0 & 1023);
        unsigned short* qdst = qg + (row0 + r) * DIM + c;
        *(bf16x8*)qdst       = *(const bf16x8*)&tr[0][r * LDP + c];
        *(bf16x8*)(qdst + 8) = *(const bf16x8*)&tr[0][r * LDP + c + 8];
        unsigned short* kdst = kg + (row0 + r) * DIM + c;
        *(bf16x8*)kdst       = *(const bf16x8*)&tr[1][r * LDP + c];
        *(bf16x8*)(kdst + 8) = *(const bf16x8*)&tr[1][r * LDP + c + 8];
        unsigned short* vdst = vtg + (b * 64 + r) * SEQ + s0 + c;
        *(bf16x8*)vdst       = *(const bf16x8*)&tr[2][r * LDP + c];
        *(bf16x8*)(vdst + 8) = *(const bf16x8*)&tr[2][r * LDP + c + 8];
    }
}

// ---------------- Kernel 2: split-K flash attention partial ----------------
// 4-wave blocks, 64-row q-tiles, dbuf K/V, XOR chunk-swizzle, single
// barrier/tile (round-12 inner loop). CHUNK=6: 30 chunks/batch, grid 960,
// exact-LPT dispatch via kOrder. Partials (qt>=6 only): acc bf16 lane-
// native, m/l fp32.
__global__ __launch_bounds__(256, 4) void attn_partial(
    const unsigned short* __restrict__ qg, const unsigned short* __restrict__ kg,
    const unsigned short* __restrict__ vtg, float* __restrict__ out,
    unsigned short* __restrict__ part_acc, float* __restrict__ part_ml)
{
    __shared__ unsigned short Ks[2][64 * 64];
    __shared__ unsigned short Vs[2][64 * 64];
    __shared__ unsigned short Ps[4][16 * 64];

    const int tid = threadIdx.x;
    const int w = tid >> 6, lane = tid & 63;
    const int l15 = lane & 15, l4 = lane >> 4;

    const int orig = blockIdx.x;
    const int blk = (orig & 7) * 120 + (orig >> 3);  // 960 = 8*120, bijective
    const int b = blk / 30;
    const int c = kOrder[blk % 30];      // exact LPT: longest chains first
    int qt, ch, nch;                     // chunk decode (30 chunks per batch)
    if (c < 6)       { qt = c;                           ch = 0;     nch = 1; }
    else if (c < 18) { const int t = c - 6;  qt = 6  + (t >> 1); ch = t & 1; nch = 2; }
    else             { const int t = c - 18; qt = 12 + t / 3;    ch = t % 3; nch = 3; }
    const int q0 = qt * 64;
    const int t0 = ch * 6;
    const int t1 = min(t0 + 6, qt + 1);

    // Q fragments (B-operand), scale pre-folded
    const unsigned short* qp = qg + ((size_t)(b * SEQ + q0 + w * 16 + l15)) * DIM + l4 * 8;
    const bf16x8 qf0 = *(const bf16x8*)qp;
    const bf16x8 qf1 = *(const bf16x8*)(qp + 32);

    // staging: thread (row sr, chunks 2*sc4, 2*sc4+1); swizzled LDS offsets
    const int sr = tid >> 2, sc4 = tid & 3;
    const unsigned short* kbase = kg + (size_t)b * SEQ * DIM + (size_t)sr * DIM + sc4 * 16;
    const unsigned short* vbase = vtg + ((size_t)b * 64 + sr) * SEQ + sc4 * 16;
    const int woff0 = sr * 64 + (((sc4 * 2)     ^ (sr & 7)) << 3);
    const int woff1 = sr * 64 + (((sc4 * 2 + 1) ^ (sr & 7)) << 3);

    // read-side swizzled chunk offset (row&7 == l15&7 for all frag rows)
    const int rc0 = (l4 ^ (l15 & 7)) << 3;

    // prologue: stage tile t0 into buffer 0
    size_t koff = (size_t)t0 * 64 * DIM;
    size_t voff = (size_t)t0 * 64;
    bf16x8 rk0 = *(const bf16x8*)(kbase + koff);
    bf16x8 rk1 = *(const bf16x8*)(kbase + koff + 8);
    bf16x8 rv0 = *(const bf16x8*)(vbase + voff);
    bf16x8 rv1 = *(const bf16x8*)(vbase + voff + 8);
    *(bf16x8*)&Ks[0][woff0] = rk0; *(bf16x8*)&Ks[0][woff1] = rk1;
    *(bf16x8*)&Vs[0][woff0] = rv0; *(bf16x8*)&Vs[0][woff1] = rv1;
    __syncthreads();

    f32x4 acc[4] = {};
    float m_run = -1e30f, l_run = 0.f;

    for (int tt = t0; tt < t1; ++tt) {
        const int cur = (tt - t0) & 1;
        const bool pf = (tt + 1 < t1);
        if (pf) {
            const size_t kn = (size_t)(tt + 1) * 64;
            rk0 = *(const bf16x8*)(kbase + kn * DIM);
            rk1 = *(const bf16x8*)(kbase + kn * DIM + 8);
            rv0 = *(const bf16x8*)(vbase + kn);
            rv1 = *(const bf16x8*)(vbase + kn + 8);
        }

        // S^T = K . Q : lane holds S[k=nb*16+l4*4+r][q=l15]
        f32x4 s[4];
        __builtin_amdgcn_s_setprio(1);
        #pragma unroll
        for (int nb = 0; nb < 4; ++nb) {
            const int krow = (nb * 16 + l15) * 64;
            const bf16x8 kf0 = *(const bf16x8*)&Ks[cur][krow + rc0];
            const bf16x8 kf1 = *(const bf16x8*)&Ks[cur][krow + (rc0 ^ 32)];
            f32x4 sv = {0.f, 0.f, 0.f, 0.f};
            sv = MFMA16(kf0, qf0, sv, 0, 0, 0);
            sv = MFMA16(kf1, qf1, sv, 0, 0, 0);
            s[nb] = sv;
        }
        __builtin_amdgcn_s_setprio(0);

        if (tt == qt) {  // causal mask on diagonal tile
            const int qabs = q0 + w * 16 + l15;
            #pragma unroll
            for (int nb = 0; nb < 4; ++nb)
                #pragma unroll
                for (int r = 0; r < 4; ++r)
                    if (tt * 64 + nb * 16 + l4 * 4 + r > qabs) s[nb][r] = -1e30f;
        }

        // softmax for q-row l15: 16 in-lane + 2-shfl butterfly over l4
        float pmax = s[0][0];
        #pragma unroll
        for (int nb = 0; nb < 4; ++nb)
            #pragma unroll
            for (int r = 0; r < 4; ++r) pmax = fmaxf(pmax, s[nb][r]);
        pmax = fmaxf(pmax, __shfl_xor(pmax, 16));
        pmax = fmaxf(pmax, __shfl_xor(pmax, 32));

        const float mnew = fmaxf(m_run, pmax);
        const float scf = __expf(m_run - mnew);
        m_run = mnew;

        float psum = 0.f;
        #pragma unroll
        for (int nb = 0; nb < 4; ++nb)
            #pragma unroll
            for (int r = 0; r < 4; ++r) {
                s[nb][r] = __expf(s[nb][r] - mnew);
                psum += s[nb][r];
            }
        psum += __shfl_xor(psum, 16);
        psum += __shfl_xor(psum, 32);
        l_run = l_run * scf + psum;

        #pragma unroll
        for (int r = 0; r < 4; ++r) {  // acc row r = q-row l4*4+r
            const float srw = __shfl(scf, l4 * 4 + r);
            acc[0][r] *= srw; acc[1][r] *= srw; acc[2][r] *= srw; acc[3][r] *= srw;
        }

        // P -> swizzled wave-private LDS (b64), then A-frag readback
        const int psbase = l15 * 64 + (l4 & 1) * 4;
        const int pch = l4 >> 1;
        #pragma unroll
        for (int nb = 0; nb < 4; ++nb) {
            const unsigned long long v =
                (unsigned long long)pk2(s[nb][0], s[nb][1]) |
                ((unsigned long long)pk2(s[nb][2], s[nb][3]) << 32);
            *(unsigned long long*)&Ps[w][psbase + (((2 * nb + pch) ^ (l15 & 7)) << 3)] = v;
        }
        const bf16x8 pa0 = *(const bf16x8*)&Ps[w][l15 * 64 + rc0];
        const bf16x8 pa1 = *(const bf16x8*)&Ps[w][l15 * 64 + (rc0 ^ 32)];

        __builtin_amdgcn_s_setprio(1);
        #pragma unroll
        for (int nb2 = 0; nb2 < 4; ++nb2) {
            const int vrow = (nb2 * 16 + l15) * 64;
            const bf16x8 vb0 = *(const bf16x8*)&Vs[cur][vrow + rc0];
            const bf16x8 vb1 = *(const bf16x8*)&Vs[cur][vrow + (rc0 ^ 32)];
            acc[nb2] = MFMA16(pa0, vb0, acc[nb2], 0, 0, 0);
            acc[nb2] = MFMA16(pa1, vb1, acc[nb2], 0, 0, 0);
        }
        __builtin_amdgcn_s_setprio(0);

        if (pf) {
            *(bf16x8*)&Ks[cur ^ 1][woff0] = rk0; *(bf16x8*)&Ks[cur ^ 1][woff1] = rk1;
            *(bf16x8*)&Vs[cur ^ 1][woff0] = rv0; *(bf16x8*)&Vs[cur ^ 1][woff1] = rv1;
        }
        __syncthreads();  // single barrier per tile
    }

    if (nch == 1) {  // qt <= 5: full k-range done here, write final output
        const float inv = 1.0f / l_run;
        #pragma unroll
        for (int r = 0; r < 4; ++r) {
            const float ir = __shfl(inv, l4 * 4 + r);
            const size_t row = (size_t)(b * SEQ + q0 + w * 16 + l4 * 4 + r);
            #pragma unroll
            for (int nb2 = 0; nb2 < 4; ++nb2)
                out[row * DIM + nb2 * 16 + l15] = acc[nb2][r] * ir;
        }
    } else {         // lane-native partial: 2 coalesced bf16x8 stores
        const size_t slot = (size_t)((b * 10 + (qt - 6)) * 3 + ch);
        unsigned short* pa = part_acc + slot * 4096 + (size_t)(w * 64 + lane) * 16;
        bf16x8 o0, o1;
        #pragma unroll
        for (int nb2 = 0; nb2 < 2; ++nb2)
            #pragma unroll
            for (int r = 0; r < 4; ++r) {
                o0[nb2 * 4 + r] = (short)f2bf(acc[nb2][r]);
                o1[nb2 * 4 + r] = (short)f2bf(acc[nb2 + 2][r]);
            }
        *(bf16x8*)pa       = o0;
        *(bf16x8*)(pa + 8) = o1;
        if (l4 == 0) {
            float* pm = part_ml + slot * 128;
            pm[w * 16 + l15]      = m_run;
            pm[64 + w * 16 + l15] = l_run;
        }
    }
}

// ---------------- Kernel 3: split-K combine (qt >= 6, <=3 chunks) ----------
__global__ __launch_bounds__(256) void combine(
    const unsigned short* __restrict__ part_acc,
    const float* __restrict__ part_ml, float* __restrict__ out)
{
    const int orig = blockIdx.x;
    const int blk = (orig & 7) * 40 + (orig >> 3);   // 320 = 8*40, bijective
    const int b = blk / 10, qt10 = blk % 10;
    const int qt = qt10 + 6;
    const int nch = (qt <= 11) ? 2 : 3;
    const int tid = threadIdx.x;
    const int w2 = tid >> 6, lane = tid & 63;
    const int l15 = lane & 15, l4 = lane >> 4;
    const size_t base0 = (size_t)(b * 10 + qt10) * 3;

    float mv[3][4], lv[3][4], M[4];
    #pragma unroll
    for (int r = 0; r < 4; ++r) M[r] = -1e30f;
    #pragma unroll
    for (int cc = 0; cc < 3; ++cc) {
        if (cc < nch) {
            const float* pm = part_ml + (base0 + cc) * 128;
            #pragma unroll
            for (int r = 0; r < 4; ++r) {
                mv[cc][r] = pm[w2 * 16 + l4 * 4 + r];
                lv[cc][r] = pm[64 + w2 * 16 + l4 * 4 + r];
                M[r] = fmaxf(M[r], mv[cc][r]);
            }
        } else {
            #pragma unroll
            for (int r = 0; r < 4; ++r) { mv[cc][r] = -1e30f; lv[cc][r] = 0.f; }
        }
    }
    float o[16], L[4];
    #pragma unroll
    for (int i = 0; i < 16; ++i) o[i] = 0.f;
    #pragma unroll
    for (int r = 0; r < 4; ++r) L[r] = 0.f;
    #pragma unroll
    for (int cc = 0; cc < 3; ++cc) {
        if (cc < nch) {
            float wsc[4];
            #pragma unroll
            for (int r = 0; r < 4; ++r) {
                wsc[r] = __expf(mv[cc][r] - M[r]);
                L[r] += wsc[r] * lv[cc][r];
            }
            const unsigned short* pa =
                part_acc + (base0 + cc) * 4096 + (size_t)(w2 * 64 + lane) * 16;
            const ushort8 t0 = *(const ushort8*)pa;
            const ushort8 t1 = *(const ushort8*)(pa + 8);
            #pragma unroll
            for (int i = 0; i < 8; ++i) {
                o[i]     += wsc[i & 3] * bf2f(t0[i]);
                o[i + 8] += wsc[i & 3] * bf2f(t1[i]);
            }
        }
    }
    float inv[4];
    #pragma unroll
    for (int r = 0; r < 4; ++r) inv[r] = 1.0f / L[r];
    #pragma unroll
    for (int nb2 = 0; nb2 < 4; ++nb2)
        #pragma unroll
        for (int r = 0; r < 4; ++r) {
            const size_t row = (size_t)(b * SEQ + qt * 64 + w2 * 16 + l4 * 4 + r);
            out[row * DIM + nb2 * 16 + l15] = o[nb2 * 4 + r] * inv[r];
        }
}

extern "C" void kernel_launch(void* const* d_in, const int* in_sizes, int n_in,
                              void* d_out, int out_size, void* d_ws, size_t ws_size,
                              hipStream_t stream) {
    const float* x  = (const float*)d_in[0];
    const float* Wq = (const float*)d_in[1];
    const float* Wk = (const float*)d_in[2];
    const float* Wv = (const float*)d_in[3];
    float* outp = (float*)d_out;

    // ws: q | k | vT (bf16, 4MB each) | part_acc (bf16, 7.9MB) | part_ml (fp32)
    unsigned short* qw  = (unsigned short*)d_ws;
    unsigned short* kw  = qw + (size_t)NB * SEQ * DIM;
    unsigned short* vtw = kw + (size_t)NB * SEQ * DIM;
    unsigned short* pacc = vtw + (size_t)NB * SEQ * DIM;
    float* pml = (float*)(pacc + (size_t)NB * 10 * 3 * 4096);

    qkv_proj<<<NB * SEQ / 64, 256, 0, stream>>>(x, Wq, Wk, Wv, qw, kw, vtw);
    attn_partial<<<NB * 30, 256, 0, stream>>>(qw, kw, vtw, outp, pacc, pml);
    combine<<<NB * 10, 256, 0, stream>>>(pacc, pml, outp);
}